// Round 5
// baseline (424.195 us; speedup 1.0000x reference)
//
#include <hip/hip_runtime.h>
#include <hip/hip_cooperative_groups.h>

namespace cg = cooperative_groups;

#define N_NODES 100000
#define N_EDGES 1600000
#define F_IN    256
#define F_HID   128
#define F_OUT   16

#define BSHIFT  9
#define BNODES  512
#define NB      196                 // ceil(100000/512)
#define ECAP    16384               // per-bucket capacity (mean 8163; +90 sigma safe)
#define CHUNK   4096
#define NCHUNK  ((N_EDGES + CHUNK - 1) / CHUNK)   // 391

typedef __attribute__((ext_vector_type(8))) short short8;
typedef __attribute__((ext_vector_type(4))) float float4v;

__device__ __forceinline__ unsigned int bf16_rn(float f) {
    unsigned int u = __float_as_uint(f);
    return (u + 0x7FFFu + ((u >> 16) & 1u)) >> 16;
}
// v_cvt_pk_bf16_f32: dst = bf16(lo) | bf16(hi)<<16, RNE — bit-identical to bf16_rn
__device__ __forceinline__ unsigned int cvtpk(float lo, float hi) {
    unsigned int r;
    asm("v_cvt_pk_bf16_f32 %0, %1, %2" : "=v"(r) : "v"(lo), "v"(hi));
    return r;
}
__device__ __forceinline__ float blo(unsigned int u) { return __uint_as_float(u << 16); }
__device__ __forceinline__ float bhi(unsigned int u) { return __uint_as_float(u & 0xFFFF0000u); }
__device__ __forceinline__ float bfu(unsigned short u) { return __uint_as_float(((unsigned int)u) << 16); }

// ============ fused CSR build: binit + transW + binscatter + finalize ============
// One cooperative kernel, 391 blocks x 512 threads (co-resident: <=2 blocks/CU,
// 1024 thr/CU, 6.4 KB LDS). grid.sync() replaces 3 kernel-boundary drains.

__global__ __launch_bounds__(512) void k_csr(const int* __restrict__ rowi,
                                             const int* __restrict__ coli,
                                             const float* __restrict__ W1,
                                             int* __restrict__ bcur,
                                             unsigned int* __restrict__ ebuf,
                                             int* __restrict__ rp_start,
                                             int* __restrict__ rp_end,
                                             float* __restrict__ dinv,
                                             int* __restrict__ esrc,
                                             ushort* __restrict__ Wt) {
    cg::grid_group grid = cg::this_grid();
    __shared__ int cnt[NB], gbase[NB], run[NB];
    __shared__ int ndeg[BNODES], sc[BNODES];
    const int tid  = threadIdx.x;            // 0..511
    const int bid  = blockIdx.x;
    const int gtid = bid * 512 + tid;

    // ---- P0: bcur init + W1 -> bf16 transposed Wt[col][k] ----
    if (gtid < NB) bcur[gtid] = gtid * ECAP;
    if (gtid < F_IN * F_HID) {
        int c = gtid & 127, k = gtid >> 7;
        Wt[c * 256 + k] = (ushort)cvtpk(W1[k * 128 + c], 0.f);
    }
    grid.sync();

    // ---- P1: bucketed scatter (one 4096-edge chunk per block) ----
    if (bid < NCHUNK) {
        int e0 = bid * CHUNK;
        for (int i = tid; i < NB; i += 512) { cnt[i] = 0; run[i] = 0; }
        __syncthreads();
        int d[8], s[8];
        #pragma unroll
        for (int i = 0; i < 8; i++) {
            int e = e0 + i * 512 + tid;
            if (e < N_EDGES) {
                d[i] = coli[e]; s[i] = rowi[e];
                atomicAdd(&cnt[d[i] >> BSHIFT], 1);
            } else d[i] = -1;
        }
        __syncthreads();
        for (int i = tid; i < NB; i += 512)
            gbase[i] = cnt[i] ? atomicAdd(&bcur[i], cnt[i]) : 0;
        __syncthreads();
        #pragma unroll
        for (int i = 0; i < 8; i++) {
            if (d[i] >= 0) {
                int b = d[i] >> BSHIFT;
                int off = atomicAdd(&run[b], 1);
                ebuf[gbase[b] + off] = ((unsigned int)(d[i] & 511) << 17) | (unsigned int)s[i];
            }
        }
    }
    grid.sync();

    // ---- P2: per-bucket counting sort -> CSR + dinv (blocks < NB) ----
    if (bid < NB) {
        int nb0 = bid << BSHIFT;
        int ebeg = bid * ECAP, eend = bcur[bid];
        ndeg[tid] = 0;
        __syncthreads();
        for (int e = ebeg + tid; e < eend; e += 512)
            atomicAdd(&ndeg[ebuf[e] >> 17], 1);
        __syncthreads();
        sc[tid] = ndeg[tid];
        __syncthreads();
        for (int off = 1; off < BNODES; off <<= 1) {
            int v = (tid >= off) ? sc[tid - off] : 0;
            __syncthreads();
            sc[tid] += v;
            __syncthreads();
        }
        {
            int n = nb0 + tid;
            int deg = ndeg[tid];
            int excl = sc[tid] - deg;
            if (n < N_NODES) {
                rp_start[n] = ebeg + excl;
                rp_end[n]   = ebeg + excl + deg;
                dinv[n]     = rsqrtf(1.0f + (float)deg);
            }
            ndeg[tid] = excl;
        }
        __syncthreads();
        for (int e = ebeg + tid; e < eend; e += 512) {
            unsigned int p = ebuf[e];
            int off = atomicAdd(&ndeg[p >> 17], 1);
            esrc[ebeg + off] = (int)(p & 0x1FFFFu);
        }
    }
}

// ============ GEMM1 (MFMA bf16, barrier-free K-loop) ============

__global__ __launch_bounds__(256) void k_gemm1(const float* __restrict__ x,
                                               const ushort* __restrict__ Wt,
                                               const float* __restrict__ dinv,
                                               ushort* __restrict__ g1) {
    __shared__ ushort Bl[128 * 256];      // 64 KB, chunk-swizzled
    const int tid = threadIdx.x;
    const int w = tid >> 6;
    const int l = tid & 63;
    const int m = l & 15;
    const int q = l >> 4;
    const int R0 = blockIdx.x * 128;

    {
        const uint4* Wg = (const uint4*)Wt;
        uint4* Bl4 = (uint4*)Bl;
        #pragma unroll
        for (int it = 0; it < 16; it++) {
            int i = it * 256 + tid;
            int c = i >> 5, j = i & 31;
            Bl4[c * 32 + (j ^ (c & 7))] = Wg[i];
        }
    }
    __syncthreads();   // the only barrier

    int r0 = R0 + w * 32 + m;      if (r0 > N_NODES - 1) r0 = N_NODES - 1;
    int r1 = R0 + w * 32 + 16 + m; if (r1 > N_NODES - 1) r1 = N_NODES - 1;
    const float* xr0 = &x[(size_t)r0 * F_IN + q * 8];
    const float* xr1 = &x[(size_t)r1 * F_IN + q * 8];
    const short8* Bl8 = (const short8*)Bl;

    float4v acc[2][8];
    #pragma unroll
    for (int i = 0; i < 2; i++)
        #pragma unroll
        for (int j = 0; j < 8; j++) acc[i][j] = (float4v){0.f, 0.f, 0.f, 0.f};

    #pragma unroll 2
    for (int kt = 0; kt < F_IN; kt += 32) {
        float4 a0 = *(const float4*)&xr0[kt];
        float4 a1 = *(const float4*)&xr0[kt + 4];
        float4 b0 = *(const float4*)&xr1[kt];
        float4 b1 = *(const float4*)&xr1[kt + 4];
        short8 af0, af1;
        ((uint*)&af0)[0] = cvtpk(a0.x, a0.y); ((uint*)&af0)[1] = cvtpk(a0.z, a0.w);
        ((uint*)&af0)[2] = cvtpk(a1.x, a1.y); ((uint*)&af0)[3] = cvtpk(a1.z, a1.w);
        ((uint*)&af1)[0] = cvtpk(b0.x, b0.y); ((uint*)&af1)[1] = cvtpk(b0.z, b0.w);
        ((uint*)&af1)[2] = cvtpk(b1.x, b1.y); ((uint*)&af1)[3] = cvtpk(b1.z, b1.w);
        int jq = (kt >> 3) + q;
        #pragma unroll
        for (int n = 0; n < 8; n++) {
            int col = n * 16 + m;
            short8 bfr = Bl8[col * 32 + (jq ^ (col & 7))];
            acc[0][n] = __builtin_amdgcn_mfma_f32_16x16x32_bf16(af0, bfr, acc[0][n], 0, 0, 0);
            acc[1][n] = __builtin_amdgcn_mfma_f32_16x16x32_bf16(af1, bfr, acc[1][n], 0, 0, 0);
        }
    }

    const int rbase = R0 + w * 32 + q * 4;
    float dv0[4], dv1[4];
    #pragma unroll
    for (int r = 0; r < 4; r++) {
        int v0 = rbase + r;      dv0[r] = (v0 < N_NODES) ? dinv[v0] : 0.f;
        int v1 = rbase + 16 + r; dv1[r] = (v1 < N_NODES) ? dinv[v1] : 0.f;
    }
    #pragma unroll
    for (int n = 0; n < 8; n++) {
        #pragma unroll
        for (int r = 0; r < 4; r++) {
            int v0 = rbase + r;
            if (v0 < N_NODES) {
                float f = dv0[r] * acc[0][n][r];
                g1[v0 * F_HID + n * 16 + m] = (ushort)cvtpk(f, f);
            }
            int v1 = rbase + 16 + r;
            if (v1 < N_NODES) {
                float f = dv1[r] * acc[1][n][r];
                g1[v1 * F_HID + n * 16 + m] = (ushort)cvtpk(f, f);
            }
        }
    }
}

// ==== fused agg1 + GEMM2, ZERO barriers: W2 in registers, 16 nodes/block ====
// (exact 73us structure; both restructures of this kernel regressed)

__global__ __launch_bounds__(256) void k_agg1g2(const int* __restrict__ rp_start,
                                                const int* __restrict__ rp_end,
                                                const int* __restrict__ esrc,
                                                const float* __restrict__ dinv,
                                                const unsigned int* __restrict__ g1,
                                                const float* __restrict__ b1,
                                                const float* __restrict__ W2,
                                                ushort* __restrict__ g2b) {
    __shared__ float hl[4][132];
    const int tid  = threadIdx.x;
    const int wave = tid >> 6;
    const int lane = tid & 63;
    const int col  = lane & 15, part = lane >> 4;

    // W2 column cache: w2r[i] = W2[(i*4+part)*16 + col] = W2[i*64 + lane] (coalesced)
    float w2r[32];
    #pragma unroll
    for (int i = 0; i < 32; i++) w2r[i] = W2[i * 64 + lane];

    float2 bb = ((const float2*)b1)[lane];

    #pragma unroll 1
    for (int j = 0; j < 4; j++) {
        const int node = blockIdx.x * 16 + j * 4 + wave;   // 6250*16 == N_NODES
        int s = rp_start[node], t = rp_end[node];
        unsigned int u = g1[node * 64 + lane];             // self-loop
        float ax = blo(u), ay = bhi(u);
        int e = s;
        for (; e + 7 < t; e += 8) {
            int r0 = esrc[e],     r1 = esrc[e + 1], r2 = esrc[e + 2], r3 = esrc[e + 3];
            int r4 = esrc[e + 4], r5 = esrc[e + 5], r6 = esrc[e + 6], r7 = esrc[e + 7];
            unsigned int u0 = g1[r0 * 64 + lane], u1 = g1[r1 * 64 + lane];
            unsigned int u2 = g1[r2 * 64 + lane], u3 = g1[r3 * 64 + lane];
            unsigned int u4 = g1[r4 * 64 + lane], u5 = g1[r5 * 64 + lane];
            unsigned int u6 = g1[r6 * 64 + lane], u7 = g1[r7 * 64 + lane];
            ax += blo(u0) + blo(u1) + blo(u2) + blo(u3)
                + blo(u4) + blo(u5) + blo(u6) + blo(u7);
            ay += bhi(u0) + bhi(u1) + bhi(u2) + bhi(u3)
                + bhi(u4) + bhi(u5) + bhi(u6) + bhi(u7);
        }
        for (; e + 3 < t; e += 4) {
            int r0 = esrc[e], r1 = esrc[e + 1], r2 = esrc[e + 2], r3 = esrc[e + 3];
            unsigned int u0 = g1[r0 * 64 + lane], u1 = g1[r1 * 64 + lane];
            unsigned int u2 = g1[r2 * 64 + lane], u3 = g1[r3 * 64 + lane];
            ax += blo(u0) + blo(u1) + blo(u2) + blo(u3);
            ay += bhi(u0) + bhi(u1) + bhi(u2) + bhi(u3);
        }
        for (; e < t; e++) {
            unsigned int u0 = g1[esrc[e] * 64 + lane];
            ax += blo(u0); ay += bhi(u0);
        }
        float wv = dinv[node];
        hl[wave][lane * 2]     = fmaxf(fmaf(wv, ax, bb.x), 0.0f);
        hl[wave][lane * 2 + 1] = fmaxf(fmaf(wv, ay, bb.y), 0.0f);
        // no barrier: wave-private strip, lgkmcnt orders within the wave

        float acc = 0.f;
        #pragma unroll
        for (int i = 0; i < 32; i++)
            acc = fmaf(hl[wave][i * 4 + part], w2r[i], acc);
        acc += __shfl_xor(acc, 16);
        acc += __shfl_xor(acc, 32);
        if (lane < 16) g2b[node * 16 + col] = (ushort)bf16_rn(wv * acc);
    }
}

// ============ aggregate layer 2 (bf16 g2, 8-deep) ============

__global__ __launch_bounds__(256) void k_agg2(const int* __restrict__ rp_start,
                                              const int* __restrict__ rp_end,
                                              const int* __restrict__ esrc,
                                              const float* __restrict__ dinv,
                                              const ushort* __restrict__ g2b,
                                              const float* __restrict__ b2,
                                              float* __restrict__ out) {
    int gid = blockIdx.x * 256 + threadIdx.x;
    int node = gid >> 4;
    int f = gid & 15;
    if (node >= N_NODES) return;
    int s = rp_start[node], t = rp_end[node];
    float acc = bfu(g2b[node * 16 + f]);
    int e = s;
    for (; e + 7 < t; e += 8) {
        float a0 = bfu(g2b[esrc[e] * 16 + f]),     a1 = bfu(g2b[esrc[e + 1] * 16 + f]);
        float a2 = bfu(g2b[esrc[e + 2] * 16 + f]), a3 = bfu(g2b[esrc[e + 3] * 16 + f]);
        float a4 = bfu(g2b[esrc[e + 4] * 16 + f]), a5 = bfu(g2b[esrc[e + 5] * 16 + f]);
        float a6 = bfu(g2b[esrc[e + 6] * 16 + f]), a7 = bfu(g2b[esrc[e + 7] * 16 + f]);
        acc += a0 + a1 + a2 + a3 + a4 + a5 + a6 + a7;
    }
    for (; e + 3 < t; e += 4) {
        acc += bfu(g2b[esrc[e] * 16 + f]) + bfu(g2b[esrc[e + 1] * 16 + f])
             + bfu(g2b[esrc[e + 2] * 16 + f]) + bfu(g2b[esrc[e + 3] * 16 + f]);
    }
    for (; e < t; e++) acc += bfu(g2b[esrc[e] * 16 + f]);
    out[node * 16 + f] = fmaf(dinv[node], acc, b2[f]);
}

// ======================= launch =======================

extern "C" void kernel_launch(void* const* d_in, const int* in_sizes, int n_in,
                              void* d_out, int out_size, void* d_ws, size_t ws_size,
                              hipStream_t stream) {
    const float* x   = (const float*)d_in[0];
    const int*   ei  = (const int*)d_in[1];
    const float* W1  = (const float*)d_in[2];
    const float* b1  = (const float*)d_in[3];
    const float* W2  = (const float*)d_in[4];
    const float* b2  = (const float*)d_in[5];
    float* out = (float*)d_out;

    const int* rowi = ei;             // sources
    const int* coli = ei + N_EDGES;   // targets

    char* ws = (char*)d_ws;
    int*          bcur     = (int*)(ws + 0);             // 784 B
    int*          rp_start = (int*)(ws + 8192);          // 400 KB
    int*          rp_end   = (int*)(ws + 524288);        // 400 KB
    float*        dinv     = (float*)(ws + 1048576);     // 400 KB
    unsigned int* ebuf     = (unsigned int*)(ws + 2097152);   // 12.85 MB (196*16384*4)
    int*          esrc     = (int*)(ws + 16777216);      // 12.85 MB
    ushort*       Wt       = (ushort*)(ws + 31457280);   // 64 KB
    ushort*       g1       = (ushort*)(ws + 33554432);   // 25.6 MB bf16
    ushort*       g2b      = (ushort*)(ws + 62914560);   // 3.2 MB bf16

    {
        void* args[] = { (void*)&rowi, (void*)&coli, (void*)&W1,
                         (void*)&bcur, (void*)&ebuf,
                         (void*)&rp_start, (void*)&rp_end,
                         (void*)&dinv, (void*)&esrc, (void*)&Wt };
        hipLaunchCooperativeKernel((void*)k_csr, dim3(NCHUNK), dim3(512),
                                   args, 0, stream);
    }

    k_gemm1     <<<(N_NODES + 127) / 128, 256, 0, stream>>>(x, Wt, dinv, g1);
    k_agg1g2    <<<N_NODES / 16, 256, 0, stream>>>(rp_start, rp_end, esrc, dinv,
                                                   (const unsigned int*)g1, b1, W2, g2b);
    k_agg2      <<<(N_NODES * 16 + 255) / 256, 256, 0, stream>>>(rp_start, rp_end, esrc,
                                                                 dinv, g2b, b2, out);
}

// Round 6
// 327.871 us; speedup vs baseline: 1.2938x; 1.2938x over previous
//
#include <hip/hip_runtime.h>

#define N_NODES 100000
#define N_EDGES 1600000
#define F_IN    256
#define F_HID   128
#define F_OUT   16

#define BSHIFT  9
#define BNODES  512
#define NB      196                 // ceil(100000/512)
#define ECAP    16384               // per-bucket capacity (mean 8163; +90 sigma safe)
#define CHUNK   4096
#define NCHUNK  ((N_EDGES + CHUNK - 1) / CHUNK)   // 391

typedef __attribute__((ext_vector_type(8))) short short8;
typedef __attribute__((ext_vector_type(4))) float float4v;

__device__ __forceinline__ unsigned int bf16_rn(float f) {
    unsigned int u = __float_as_uint(f);
    return (u + 0x7FFFu + ((u >> 16) & 1u)) >> 16;
}
// v_cvt_pk_bf16_f32: dst = bf16(lo) | bf16(hi)<<16, RNE — bit-identical to bf16_rn
__device__ __forceinline__ unsigned int cvtpk(float lo, float hi) {
    unsigned int r;
    asm("v_cvt_pk_bf16_f32 %0, %1, %2" : "=v"(r) : "v"(lo), "v"(hi));
    return r;
}
__device__ __forceinline__ float blo(unsigned int u) { return __uint_as_float(u << 16); }
__device__ __forceinline__ float bhi(unsigned int u) { return __uint_as_float(u & 0xFFFF0000u); }
__device__ __forceinline__ float bfu(unsigned short u) { return __uint_as_float(((unsigned int)u) << 16); }

// ======================= bucketed CSR build (fixed capacity) =======================

__global__ __launch_bounds__(256) void k_binit(int* __restrict__ bcur) {
    int i = threadIdx.x;
    if (i < NB) bcur[i] = i * ECAP;
}

__global__ __launch_bounds__(256) void k_binscatter(const int* __restrict__ rowi,
                                                    const int* __restrict__ coli,
                                                    int* __restrict__ bcur,
                                                    unsigned int* __restrict__ ebuf) {
    __shared__ int cnt[NB], gbase[NB], run[NB];
    int tid = threadIdx.x;
    int e0 = blockIdx.x * CHUNK;
    for (int i = tid; i < NB; i += 256) { cnt[i] = 0; run[i] = 0; }
    __syncthreads();
    int d[16], s[16];
    #pragma unroll
    for (int i = 0; i < 16; i++) {
        int e = e0 + i * 256 + tid;
        if (e < N_EDGES) {
            d[i] = coli[e]; s[i] = rowi[e];
            atomicAdd(&cnt[d[i] >> BSHIFT], 1);
        } else d[i] = -1;
    }
    __syncthreads();
    for (int i = tid; i < NB; i += 256)
        gbase[i] = cnt[i] ? atomicAdd(&bcur[i], cnt[i]) : 0;
    __syncthreads();
    #pragma unroll
    for (int i = 0; i < 16; i++) {
        if (d[i] >= 0) {
            int b = d[i] >> BSHIFT;
            int off = atomicAdd(&run[b], 1);
            ebuf[gbase[b] + off] = ((unsigned int)(d[i] & 511) << 17) | (unsigned int)s[i];
        }
    }
}

// 512 threads: 196 blocks (<1/CU) -> intra-block parallelism is the only lever (r3: ~-11us)
__global__ __launch_bounds__(512) void k_finalize(const int* __restrict__ bcur,
                                                  const unsigned int* __restrict__ ebuf,
                                                  int* __restrict__ rp_start,
                                                  int* __restrict__ rp_end,
                                                  float* __restrict__ dinv,
                                                  int* __restrict__ esrc) {
    __shared__ int ndeg[BNODES];
    __shared__ int sc[BNODES];
    int tid = threadIdx.x;            // 0..511
    int b   = blockIdx.x;
    int nb0 = b << BSHIFT;
    int ebeg = b * ECAP, eend = bcur[b];
    ndeg[tid] = 0;
    __syncthreads();
    for (int e = ebeg + tid; e < eend; e += 512)
        atomicAdd(&ndeg[ebuf[e] >> 17], 1);
    __syncthreads();
    sc[tid] = ndeg[tid];
    __syncthreads();
    for (int off = 1; off < BNODES; off <<= 1) {
        int v = (tid >= off) ? sc[tid - off] : 0;
        __syncthreads();
        sc[tid] += v;
        __syncthreads();
    }
    {
        int n = nb0 + tid;
        int deg = ndeg[tid];
        int excl = sc[tid] - deg;
        if (n < N_NODES) {
            rp_start[n] = ebeg + excl;
            rp_end[n]   = ebeg + excl + deg;
            dinv[n]     = rsqrtf(1.0f + (float)deg);
        }
        ndeg[tid] = excl;
    }
    __syncthreads();
    for (int e = ebeg + tid; e < eend; e += 512) {
        unsigned int p = ebuf[e];
        int off = atomicAdd(&ndeg[p >> 17], 1);
        esrc[ebeg + off] = (int)(p & 0x1FFFFu);
    }
}

// ============ W1 -> bf16 transposed Wt[col][k] ============

__global__ __launch_bounds__(256) void k_transW(const float* __restrict__ W1,
                                                ushort* __restrict__ Wt) {
    int t = blockIdx.x * 256 + threadIdx.x;
    int c = t & 127, k = t >> 7;
    Wt[c * 256 + k] = (ushort)cvtpk(W1[k * 128 + c], 0.f);
}

// ============ GEMM1 (MFMA bf16, barrier-free K-loop) ============

__global__ __launch_bounds__(256) void k_gemm1(const float* __restrict__ x,
                                               const ushort* __restrict__ Wt,
                                               const float* __restrict__ dinv,
                                               ushort* __restrict__ g1) {
    __shared__ ushort Bl[128 * 256];      // 64 KB, chunk-swizzled
    const int tid = threadIdx.x;
    const int w = tid >> 6;
    const int l = tid & 63;
    const int m = l & 15;
    const int q = l >> 4;
    const int R0 = blockIdx.x * 128;

    {
        const uint4* Wg = (const uint4*)Wt;
        uint4* Bl4 = (uint4*)Bl;
        #pragma unroll
        for (int it = 0; it < 16; it++) {
            int i = it * 256 + tid;
            int c = i >> 5, j = i & 31;
            Bl4[c * 32 + (j ^ (c & 7))] = Wg[i];
        }
    }
    __syncthreads();   // the only barrier

    int r0 = R0 + w * 32 + m;      if (r0 > N_NODES - 1) r0 = N_NODES - 1;
    int r1 = R0 + w * 32 + 16 + m; if (r1 > N_NODES - 1) r1 = N_NODES - 1;
    const float* xr0 = &x[(size_t)r0 * F_IN + q * 8];
    const float* xr1 = &x[(size_t)r1 * F_IN + q * 8];
    const short8* Bl8 = (const short8*)Bl;

    float4v acc[2][8];
    #pragma unroll
    for (int i = 0; i < 2; i++)
        #pragma unroll
        for (int j = 0; j < 8; j++) acc[i][j] = (float4v){0.f, 0.f, 0.f, 0.f};

    #pragma unroll 2
    for (int kt = 0; kt < F_IN; kt += 32) {
        float4 a0 = *(const float4*)&xr0[kt];
        float4 a1 = *(const float4*)&xr0[kt + 4];
        float4 b0 = *(const float4*)&xr1[kt];
        float4 b1 = *(const float4*)&xr1[kt + 4];
        short8 af0, af1;
        ((uint*)&af0)[0] = cvtpk(a0.x, a0.y); ((uint*)&af0)[1] = cvtpk(a0.z, a0.w);
        ((uint*)&af0)[2] = cvtpk(a1.x, a1.y); ((uint*)&af0)[3] = cvtpk(a1.z, a1.w);
        ((uint*)&af1)[0] = cvtpk(b0.x, b0.y); ((uint*)&af1)[1] = cvtpk(b0.z, b0.w);
        ((uint*)&af1)[2] = cvtpk(b1.x, b1.y); ((uint*)&af1)[3] = cvtpk(b1.z, b1.w);
        int jq = (kt >> 3) + q;
        #pragma unroll
        for (int n = 0; n < 8; n++) {
            int col = n * 16 + m;
            short8 bfr = Bl8[col * 32 + (jq ^ (col & 7))];
            acc[0][n] = __builtin_amdgcn_mfma_f32_16x16x32_bf16(af0, bfr, acc[0][n], 0, 0, 0);
            acc[1][n] = __builtin_amdgcn_mfma_f32_16x16x32_bf16(af1, bfr, acc[1][n], 0, 0, 0);
        }
    }

    const int rbase = R0 + w * 32 + q * 4;
    float dv0[4], dv1[4];
    #pragma unroll
    for (int r = 0; r < 4; r++) {
        int v0 = rbase + r;      dv0[r] = (v0 < N_NODES) ? dinv[v0] : 0.f;
        int v1 = rbase + 16 + r; dv1[r] = (v1 < N_NODES) ? dinv[v1] : 0.f;
    }
    #pragma unroll
    for (int n = 0; n < 8; n++) {
        #pragma unroll
        for (int r = 0; r < 4; r++) {
            int v0 = rbase + r;
            if (v0 < N_NODES) {
                float f = dv0[r] * acc[0][n][r];
                g1[v0 * F_HID + n * 16 + m] = (ushort)cvtpk(f, f);
            }
            int v1 = rbase + 16 + r;
            if (v1 < N_NODES) {
                float f = dv1[r] * acc[1][n][r];
                g1[v1 * F_HID + n * 16 + m] = (ushort)cvtpk(f, f);
            }
        }
    }
}

// ==== fused agg1 + GEMM2, ZERO barriers: W2 in registers, 16 nodes/block ====
// Split into two half-range dispatches (nbase param) purely so the 73us reps
// stop monopolizing the rocprof top-5 — work and per-node order bit-identical.

__global__ __launch_bounds__(256) void k_agg1g2(const int* __restrict__ rp_start,
                                                const int* __restrict__ rp_end,
                                                const int* __restrict__ esrc,
                                                const float* __restrict__ dinv,
                                                const unsigned int* __restrict__ g1,
                                                const float* __restrict__ b1,
                                                const float* __restrict__ W2,
                                                ushort* __restrict__ g2b,
                                                int nbase) {
    __shared__ float hl[4][132];
    const int tid  = threadIdx.x;
    const int wave = tid >> 6;
    const int lane = tid & 63;
    const int col  = lane & 15, part = lane >> 4;

    // W2 column cache: w2r[i] = W2[(i*4+part)*16 + col] = W2[i*64 + lane] (coalesced)
    float w2r[32];
    #pragma unroll
    for (int i = 0; i < 32; i++) w2r[i] = W2[i * 64 + lane];

    float2 bb = ((const float2*)b1)[lane];

    #pragma unroll 1
    for (int j = 0; j < 4; j++) {
        const int node = nbase + blockIdx.x * 16 + j * 4 + wave;
        int s = rp_start[node], t = rp_end[node];
        unsigned int u = g1[node * 64 + lane];             // self-loop
        float ax = blo(u), ay = bhi(u);
        int e = s;
        for (; e + 7 < t; e += 8) {
            int r0 = esrc[e],     r1 = esrc[e + 1], r2 = esrc[e + 2], r3 = esrc[e + 3];
            int r4 = esrc[e + 4], r5 = esrc[e + 5], r6 = esrc[e + 6], r7 = esrc[e + 7];
            unsigned int u0 = g1[r0 * 64 + lane], u1 = g1[r1 * 64 + lane];
            unsigned int u2 = g1[r2 * 64 + lane], u3 = g1[r3 * 64 + lane];
            unsigned int u4 = g1[r4 * 64 + lane], u5 = g1[r5 * 64 + lane];
            unsigned int u6 = g1[r6 * 64 + lane], u7 = g1[r7 * 64 + lane];
            ax += blo(u0) + blo(u1) + blo(u2) + blo(u3)
                + blo(u4) + blo(u5) + blo(u6) + blo(u7);
            ay += bhi(u0) + bhi(u1) + bhi(u2) + bhi(u3)
                + bhi(u4) + bhi(u5) + bhi(u6) + bhi(u7);
        }
        for (; e + 3 < t; e += 4) {
            int r0 = esrc[e], r1 = esrc[e + 1], r2 = esrc[e + 2], r3 = esrc[e + 3];
            unsigned int u0 = g1[r0 * 64 + lane], u1 = g1[r1 * 64 + lane];
            unsigned int u2 = g1[r2 * 64 + lane], u3 = g1[r3 * 64 + lane];
            ax += blo(u0) + blo(u1) + blo(u2) + blo(u3);
            ay += bhi(u0) + bhi(u1) + bhi(u2) + bhi(u3);
        }
        for (; e < t; e++) {
            unsigned int u0 = g1[esrc[e] * 64 + lane];
            ax += blo(u0); ay += bhi(u0);
        }
        float wv = dinv[node];
        hl[wave][lane * 2]     = fmaxf(fmaf(wv, ax, bb.x), 0.0f);
        hl[wave][lane * 2 + 1] = fmaxf(fmaf(wv, ay, bb.y), 0.0f);
        // no barrier: wave-private strip, lgkmcnt orders within the wave

        float acc = 0.f;
        #pragma unroll
        for (int i = 0; i < 32; i++)
            acc = fmaf(hl[wave][i * 4 + part], w2r[i], acc);
        acc += __shfl_xor(acc, 16);
        acc += __shfl_xor(acc, 32);
        if (lane < 16) g2b[node * 16 + col] = (ushort)bf16_rn(wv * acc);
    }
}

// ============ aggregate layer 2 (bf16 g2, 8-deep) ============

__global__ __launch_bounds__(256) void k_agg2(const int* __restrict__ rp_start,
                                              const int* __restrict__ rp_end,
                                              const int* __restrict__ esrc,
                                              const float* __restrict__ dinv,
                                              const ushort* __restrict__ g2b,
                                              const float* __restrict__ b2,
                                              float* __restrict__ out) {
    int gid = blockIdx.x * 256 + threadIdx.x;
    int node = gid >> 4;
    int f = gid & 15;
    if (node >= N_NODES) return;
    int s = rp_start[node], t = rp_end[node];
    float acc = bfu(g2b[node * 16 + f]);
    int e = s;
    for (; e + 7 < t; e += 8) {
        float a0 = bfu(g2b[esrc[e] * 16 + f]),     a1 = bfu(g2b[esrc[e + 1] * 16 + f]);
        float a2 = bfu(g2b[esrc[e + 2] * 16 + f]), a3 = bfu(g2b[esrc[e + 3] * 16 + f]);
        float a4 = bfu(g2b[esrc[e + 4] * 16 + f]), a5 = bfu(g2b[esrc[e + 5] * 16 + f]);
        float a6 = bfu(g2b[esrc[e + 6] * 16 + f]), a7 = bfu(g2b[esrc[e + 7] * 16 + f]);
        acc += a0 + a1 + a2 + a3 + a4 + a5 + a6 + a7;
    }
    for (; e + 3 < t; e += 4) {
        acc += bfu(g2b[esrc[e] * 16 + f]) + bfu(g2b[esrc[e + 1] * 16 + f])
             + bfu(g2b[esrc[e + 2] * 16 + f]) + bfu(g2b[esrc[e + 3] * 16 + f]);
    }
    for (; e < t; e++) acc += bfu(g2b[esrc[e] * 16 + f]);
    out[node * 16 + f] = fmaf(dinv[node], acc, b2[f]);
}

// ======================= launch =======================

extern "C" void kernel_launch(void* const* d_in, const int* in_sizes, int n_in,
                              void* d_out, int out_size, void* d_ws, size_t ws_size,
                              hipStream_t stream) {
    const float* x   = (const float*)d_in[0];
    const int*   ei  = (const int*)d_in[1];
    const float* W1  = (const float*)d_in[2];
    const float* b1  = (const float*)d_in[3];
    const float* W2  = (const float*)d_in[4];
    const float* b2  = (const float*)d_in[5];
    float* out = (float*)d_out;

    const int* rowi = ei;             // sources
    const int* coli = ei + N_EDGES;   // targets

    char* ws = (char*)d_ws;
    int*          bcur     = (int*)(ws + 0);             // 784 B
    int*          rp_start = (int*)(ws + 8192);          // 400 KB
    int*          rp_end   = (int*)(ws + 524288);        // 400 KB
    float*        dinv     = (float*)(ws + 1048576);     // 400 KB
    unsigned int* ebuf     = (unsigned int*)(ws + 2097152);   // 12.85 MB (196*16384*4)
    int*          esrc     = (int*)(ws + 16777216);      // 12.85 MB
    ushort*       Wt       = (ushort*)(ws + 31457280);   // 64 KB
    ushort*       g1       = (ushort*)(ws + 33554432);   // 25.6 MB bf16
    ushort*       g2b      = (ushort*)(ws + 62914560);   // 3.2 MB bf16

    k_binit     <<<1, 256, 0, stream>>>(bcur);
    k_binscatter<<<NCHUNK, 256, 0, stream>>>(rowi, coli, bcur, ebuf);
    k_finalize  <<<NB, 512, 0, stream>>>(bcur, ebuf, rp_start, rp_end, dinv, esrc);
    k_transW    <<<128, 256, 0, stream>>>(W1, Wt);

    k_gemm1     <<<(N_NODES + 127) / 128, 256, 0, stream>>>(x, Wt, dinv, g1);
    k_agg1g2    <<<N_NODES / 32, 256, 0, stream>>>(rp_start, rp_end, esrc, dinv,
                                                   (const unsigned int*)g1, b1, W2, g2b, 0);
    k_agg1g2    <<<N_NODES / 32, 256, 0, stream>>>(rp_start, rp_end, esrc, dinv,
                                                   (const unsigned int*)g1, b1, W2, g2b,
                                                   N_NODES / 2);
    k_agg2      <<<(N_NODES * 16 + 255) / 256, 256, 0, stream>>>(rp_start, rp_end, esrc,
                                                                 dinv, g2b, b2, out);
}

// Round 8
// 320.497 us; speedup vs baseline: 1.3236x; 1.0230x over previous
//
#include <hip/hip_runtime.h>

#define N_NODES 100000
#define N_EDGES 1600000
#define F_IN    256
#define F_HID   128
#define F_OUT   16

#define BSHIFT  9
#define BNODES  512
#define NB      196                 // ceil(100000/512)
#define ECAP    16384               // per-bucket capacity (mean 8163; +90 sigma safe)
#define CHUNK   4096
#define NCHUNK  ((N_EDGES + CHUNK - 1) / CHUNK)   // 391

typedef __attribute__((ext_vector_type(8))) short short8;
typedef __attribute__((ext_vector_type(4))) float float4v;

__device__ __forceinline__ unsigned int bf16_rn(float f) {
    unsigned int u = __float_as_uint(f);
    return (u + 0x7FFFu + ((u >> 16) & 1u)) >> 16;
}
// v_cvt_pk_bf16_f32: dst = bf16(lo) | bf16(hi)<<16, RNE — bit-identical to bf16_rn
__device__ __forceinline__ unsigned int cvtpk(float lo, float hi) {
    unsigned int r;
    asm("v_cvt_pk_bf16_f32 %0, %1, %2" : "=v"(r) : "v"(lo), "v"(hi));
    return r;
}
__device__ __forceinline__ float blo(unsigned int u) { return __uint_as_float(u << 16); }
__device__ __forceinline__ float bhi(unsigned int u) { return __uint_as_float(u & 0xFFFF0000u); }
__device__ __forceinline__ float bfu(unsigned short u) { return __uint_as_float(((unsigned int)u) << 16); }

// ======================= bucketed CSR build (fixed capacity) =======================

__global__ __launch_bounds__(256) void k_binit(int* __restrict__ bcur) {
    int i = threadIdx.x;
    if (i < NB) bcur[i] = i * ECAP;
}

__global__ __launch_bounds__(256) void k_binscatter(const int* __restrict__ rowi,
                                                    const int* __restrict__ coli,
                                                    int* __restrict__ bcur,
                                                    unsigned int* __restrict__ ebuf) {
    __shared__ int cnt[NB], gbase[NB], run[NB];
    int tid = threadIdx.x;
    int e0 = blockIdx.x * CHUNK;
    for (int i = tid; i < NB; i += 256) { cnt[i] = 0; run[i] = 0; }
    __syncthreads();
    int d[16], s[16];
    #pragma unroll
    for (int i = 0; i < 16; i++) {
        int e = e0 + i * 256 + tid;
        if (e < N_EDGES) {
            d[i] = coli[e]; s[i] = rowi[e];
            atomicAdd(&cnt[d[i] >> BSHIFT], 1);
        } else d[i] = -1;
    }
    __syncthreads();
    for (int i = tid; i < NB; i += 256)
        gbase[i] = cnt[i] ? atomicAdd(&bcur[i], cnt[i]) : 0;
    __syncthreads();
    #pragma unroll
    for (int i = 0; i < 16; i++) {
        if (d[i] >= 0) {
            int b = d[i] >> BSHIFT;
            int off = atomicAdd(&run[b], 1);
            ebuf[gbase[b] + off] = ((unsigned int)(d[i] & 511) << 17) | (unsigned int)s[i];
        }
    }
}

// 512 threads: 196 blocks (<1/CU) -> intra-block parallelism is the only lever (r3: ~-11us)
__global__ __launch_bounds__(512) void k_finalize(const int* __restrict__ bcur,
                                                  const unsigned int* __restrict__ ebuf,
                                                  int* __restrict__ rp_start,
                                                  int* __restrict__ rp_end,
                                                  float* __restrict__ dinv,
                                                  int* __restrict__ esrc) {
    __shared__ int ndeg[BNODES];
    __shared__ int sc[BNODES];
    int tid = threadIdx.x;            // 0..511
    int b   = blockIdx.x;
    int nb0 = b << BSHIFT;
    int ebeg = b * ECAP, eend = bcur[b];
    ndeg[tid] = 0;
    __syncthreads();
    for (int e = ebeg + tid; e < eend; e += 512)
        atomicAdd(&ndeg[ebuf[e] >> 17], 1);
    __syncthreads();
    sc[tid] = ndeg[tid];
    __syncthreads();
    for (int off = 1; off < BNODES; off <<= 1) {
        int v = (tid >= off) ? sc[tid - off] : 0;
        __syncthreads();
        sc[tid] += v;
        __syncthreads();
    }
    {
        int n = nb0 + tid;
        int deg = ndeg[tid];
        int excl = sc[tid] - deg;
        if (n < N_NODES) {
            rp_start[n] = ebeg + excl;
            rp_end[n]   = ebeg + excl + deg;
            dinv[n]     = rsqrtf(1.0f + (float)deg);
        }
        ndeg[tid] = excl;
    }
    __syncthreads();
    for (int e = ebeg + tid; e < eend; e += 512) {
        unsigned int p = ebuf[e];
        int off = atomicAdd(&ndeg[p >> 17], 1);
        esrc[ebeg + off] = (int)(p & 0x1FFFFu);
    }
}

// ============ W1 -> bf16 transposed Wt[col][k] ============

__global__ __launch_bounds__(256) void k_transW(const float* __restrict__ W1,
                                                ushort* __restrict__ Wt) {
    int t = blockIdx.x * 256 + threadIdx.x;
    int c = t & 127, k = t >> 7;
    Wt[c * 256 + k] = (ushort)cvtpk(W1[k * 128 + c], 0.f);
}

// ============ GEMM1 (MFMA bf16, barrier-free K-loop, 512-thread blocks) ============
// r6 PMC: 64KB LDS @256thr -> 2 blocks/CU -> 8 waves/CU -> Occupancy 16%, all idle.
// Fix: 512 threads / 256 rows per block, same 64KB staging (byte-identical LDS
// content, proven r6 code) -> 16 waves/CU and all 391 blocks co-resident.
// Per-output instruction sequence unchanged -> bit-identical g1.

__global__ __launch_bounds__(512) void k_gemm1(const float* __restrict__ x,
                                               const ushort* __restrict__ Wt,
                                               const float* __restrict__ dinv,
                                               ushort* __restrict__ g1) {
    __shared__ ushort Bl[128 * 256];      // 64 KB, chunk-swizzled
    const int tid = threadIdx.x;          // 0..511
    const int w = tid >> 6;               // 0..7
    const int l = tid & 63;
    const int m = l & 15;
    const int q = l >> 4;
    const int R0 = blockIdx.x * 256;

    {
        const uint4* Wg = (const uint4*)Wt;
        uint4* Bl4 = (uint4*)Bl;
        #pragma unroll
        for (int it = 0; it < 8; it++) {
            int i = it * 512 + tid;       // same i-set (0..4095) as r6, 512 writers
            int c = i >> 5, j = i & 31;
            Bl4[c * 32 + (j ^ (c & 7))] = Wg[i];
        }
    }
    __syncthreads();   // the only barrier

    int r0 = R0 + w * 32 + m;      if (r0 > N_NODES - 1) r0 = N_NODES - 1;
    int r1 = R0 + w * 32 + 16 + m; if (r1 > N_NODES - 1) r1 = N_NODES - 1;
    const float* xr0 = &x[(size_t)r0 * F_IN + q * 8];
    const float* xr1 = &x[(size_t)r1 * F_IN + q * 8];
    const short8* Bl8 = (const short8*)Bl;

    float4v acc[2][8];
    #pragma unroll
    for (int i = 0; i < 2; i++)
        #pragma unroll
        for (int j = 0; j < 8; j++) acc[i][j] = (float4v){0.f, 0.f, 0.f, 0.f};

    #pragma unroll 2
    for (int kt = 0; kt < F_IN; kt += 32) {
        float4 a0 = *(const float4*)&xr0[kt];
        float4 a1 = *(const float4*)&xr0[kt + 4];
        float4 b0 = *(const float4*)&xr1[kt];
        float4 b1 = *(const float4*)&xr1[kt + 4];
        short8 af0, af1;
        ((uint*)&af0)[0] = cvtpk(a0.x, a0.y); ((uint*)&af0)[1] = cvtpk(a0.z, a0.w);
        ((uint*)&af0)[2] = cvtpk(a1.x, a1.y); ((uint*)&af0)[3] = cvtpk(a1.z, a1.w);
        ((uint*)&af1)[0] = cvtpk(b0.x, b0.y); ((uint*)&af1)[1] = cvtpk(b0.z, b0.w);
        ((uint*)&af1)[2] = cvtpk(b1.x, b1.y); ((uint*)&af1)[3] = cvtpk(b1.z, b1.w);
        int jq = (kt >> 3) + q;
        #pragma unroll
        for (int n = 0; n < 8; n++) {
            int col = n * 16 + m;
            short8 bfr = Bl8[col * 32 + (jq ^ (col & 7))];
            acc[0][n] = __builtin_amdgcn_mfma_f32_16x16x32_bf16(af0, bfr, acc[0][n], 0, 0, 0);
            acc[1][n] = __builtin_amdgcn_mfma_f32_16x16x32_bf16(af1, bfr, acc[1][n], 0, 0, 0);
        }
    }

    const int rbase = R0 + w * 32 + q * 4;
    float dv0[4], dv1[4];
    #pragma unroll
    for (int r = 0; r < 4; r++) {
        int v0 = rbase + r;      dv0[r] = (v0 < N_NODES) ? dinv[v0] : 0.f;
        int v1 = rbase + 16 + r; dv1[r] = (v1 < N_NODES) ? dinv[v1] : 0.f;
    }
    #pragma unroll
    for (int n = 0; n < 8; n++) {
        #pragma unroll
        for (int r = 0; r < 4; r++) {
            int v0 = rbase + r;
            if (v0 < N_NODES) {
                float f = dv0[r] * acc[0][n][r];
                g1[v0 * F_HID + n * 16 + m] = (ushort)cvtpk(f, f);
            }
            int v1 = rbase + 16 + r;
            if (v1 < N_NODES) {
                float f = dv1[r] * acc[1][n][r];
                g1[v1 * F_HID + n * 16 + m] = (ushort)cvtpk(f, f);
            }
        }
    }
}

// ==== fused agg1 + GEMM2, ZERO barriers: W2 in registers, 16 nodes/block ====
// Still split into two half-range dispatches (nbase) so sub-65us kernels can
// surface in the rocprof top-5 — work and per-node order bit-identical.

__global__ __launch_bounds__(256) void k_agg1g2(const int* __restrict__ rp_start,
                                                const int* __restrict__ rp_end,
                                                const int* __restrict__ esrc,
                                                const float* __restrict__ dinv,
                                                const unsigned int* __restrict__ g1,
                                                const float* __restrict__ b1,
                                                const float* __restrict__ W2,
                                                ushort* __restrict__ g2b,
                                                int nbase) {
    __shared__ float hl[4][132];
    const int tid  = threadIdx.x;
    const int wave = tid >> 6;
    const int lane = tid & 63;
    const int col  = lane & 15, part = lane >> 4;

    // W2 column cache: w2r[i] = W2[(i*4+part)*16 + col] = W2[i*64 + lane] (coalesced)
    float w2r[32];
    #pragma unroll
    for (int i = 0; i < 32; i++) w2r[i] = W2[i * 64 + lane];

    float2 bb = ((const float2*)b1)[lane];

    #pragma unroll 1
    for (int j = 0; j < 4; j++) {
        const int node = nbase + blockIdx.x * 16 + j * 4 + wave;
        int s = rp_start[node], t = rp_end[node];
        unsigned int u = g1[node * 64 + lane];             // self-loop
        float ax = blo(u), ay = bhi(u);
        int e = s;
        for (; e + 7 < t; e += 8) {
            int r0 = esrc[e],     r1 = esrc[e + 1], r2 = esrc[e + 2], r3 = esrc[e + 3];
            int r4 = esrc[e + 4], r5 = esrc[e + 5], r6 = esrc[e + 6], r7 = esrc[e + 7];
            unsigned int u0 = g1[r0 * 64 + lane], u1 = g1[r1 * 64 + lane];
            unsigned int u2 = g1[r2 * 64 + lane], u3 = g1[r3 * 64 + lane];
            unsigned int u4 = g1[r4 * 64 + lane], u5 = g1[r5 * 64 + lane];
            unsigned int u6 = g1[r6 * 64 + lane], u7 = g1[r7 * 64 + lane];
            ax += blo(u0) + blo(u1) + blo(u2) + blo(u3)
                + blo(u4) + blo(u5) + blo(u6) + blo(u7);
            ay += bhi(u0) + bhi(u1) + bhi(u2) + bhi(u3)
                + bhi(u4) + bhi(u5) + bhi(u6) + bhi(u7);
        }
        for (; e + 3 < t; e += 4) {
            int r0 = esrc[e], r1 = esrc[e + 1], r2 = esrc[e + 2], r3 = esrc[e + 3];
            unsigned int u0 = g1[r0 * 64 + lane], u1 = g1[r1 * 64 + lane];
            unsigned int u2 = g1[r2 * 64 + lane], u3 = g1[r3 * 64 + lane];
            ax += blo(u0) + blo(u1) + blo(u2) + blo(u3);
            ay += bhi(u0) + bhi(u1) + bhi(u2) + bhi(u3);
        }
        for (; e < t; e++) {
            unsigned int u0 = g1[esrc[e] * 64 + lane];
            ax += blo(u0); ay += bhi(u0);
        }
        float wv = dinv[node];
        hl[wave][lane * 2]     = fmaxf(fmaf(wv, ax, bb.x), 0.0f);
        hl[wave][lane * 2 + 1] = fmaxf(fmaf(wv, ay, bb.y), 0.0f);
        // no barrier: wave-private strip, lgkmcnt orders within the wave

        float acc = 0.f;
        #pragma unroll
        for (int i = 0; i < 32; i++)
            acc = fmaf(hl[wave][i * 4 + part], w2r[i], acc);
        acc += __shfl_xor(acc, 16);
        acc += __shfl_xor(acc, 32);
        if (lane < 16) g2b[node * 16 + col] = (ushort)bf16_rn(wv * acc);
    }
}

// ============ aggregate layer 2 (bf16 g2, 8-deep) ============

__global__ __launch_bounds__(256) void k_agg2(const int* __restrict__ rp_start,
                                              const int* __restrict__ rp_end,
                                              const int* __restrict__ esrc,
                                              const float* __restrict__ dinv,
                                              const ushort* __restrict__ g2b,
                                              const float* __restrict__ b2,
                                              float* __restrict__ out) {
    int gid = blockIdx.x * 256 + threadIdx.x;
    int node = gid >> 4;
    int f = gid & 15;
    if (node >= N_NODES) return;
    int s = rp_start[node], t = rp_end[node];
    float acc = bfu(g2b[node * 16 + f]);
    int e = s;
    for (; e + 7 < t; e += 8) {
        float a0 = bfu(g2b[esrc[e] * 16 + f]),     a1 = bfu(g2b[esrc[e + 1] * 16 + f]);
        float a2 = bfu(g2b[esrc[e + 2] * 16 + f]), a3 = bfu(g2b[esrc[e + 3] * 16 + f]);
        float a4 = bfu(g2b[esrc[e + 4] * 16 + f]), a5 = bfu(g2b[esrc[e + 5] * 16 + f]);
        float a6 = bfu(g2b[esrc[e + 6] * 16 + f]), a7 = bfu(g2b[esrc[e + 7] * 16 + f]);
        acc += a0 + a1 + a2 + a3 + a4 + a5 + a6 + a7;
    }
    for (; e + 3 < t; e += 4) {
        acc += bfu(g2b[esrc[e] * 16 + f]) + bfu(g2b[esrc[e + 1] * 16 + f])
             + bfu(g2b[esrc[e + 2] * 16 + f]) + bfu(g2b[esrc[e + 3] * 16 + f]);
    }
    for (; e < t; e++) acc += bfu(g2b[esrc[e] * 16 + f]);
    out[node * 16 + f] = fmaf(dinv[node], acc, b2[f]);
}

// ======================= launch =======================

extern "C" void kernel_launch(void* const* d_in, const int* in_sizes, int n_in,
                              void* d_out, int out_size, void* d_ws, size_t ws_size,
                              hipStream_t stream) {
    const float* x   = (const float*)d_in[0];
    const int*   ei  = (const int*)d_in[1];
    const float* W1  = (const float*)d_in[2];
    const float* b1  = (const float*)d_in[3];
    const float* W2  = (const float*)d_in[4];
    const float* b2  = (const float*)d_in[5];
    float* out = (float*)d_out;

    const int* rowi = ei;             // sources
    const int* coli = ei + N_EDGES;   // targets

    char* ws = (char*)d_ws;
    int*          bcur     = (int*)(ws + 0);             // 784 B
    int*          rp_start = (int*)(ws + 8192);          // 400 KB
    int*          rp_end   = (int*)(ws + 524288);        // 400 KB
    float*        dinv     = (float*)(ws + 1048576);     // 400 KB
    unsigned int* ebuf     = (unsigned int*)(ws + 2097152);   // 12.85 MB (196*16384*4)
    int*          esrc     = (int*)(ws + 16777216);      // 12.85 MB
    ushort*       Wt       = (ushort*)(ws + 31457280);   // 64 KB
    ushort*       g1       = (ushort*)(ws + 33554432);   // 25.6 MB bf16
    ushort*       g2b      = (ushort*)(ws + 62914560);   // 3.2 MB bf16

    k_binit     <<<1, 256, 0, stream>>>(bcur);
    k_binscatter<<<NCHUNK, 256, 0, stream>>>(rowi, coli, bcur, ebuf);
    k_finalize  <<<NB, 512, 0, stream>>>(bcur, ebuf, rp_start, rp_end, dinv, esrc);
    k_transW    <<<128, 256, 0, stream>>>(W1, Wt);

    k_gemm1     <<<(N_NODES + 255) / 256, 512, 0, stream>>>(x, Wt, dinv, g1);
    k_agg1g2    <<<N_NODES / 32, 256, 0, stream>>>(rp_start, rp_end, esrc, dinv,
                                                   (const unsigned int*)g1, b1, W2, g2b, 0);
    k_agg1g2    <<<N_NODES / 32, 256, 0, stream>>>(rp_start, rp_end, esrc, dinv,
                                                   (const unsigned int*)g1, b1, W2, g2b,
                                                   N_NODES / 2);
    k_agg2      <<<(N_NODES * 16 + 255) / 256, 256, 0, stream>>>(rp_start, rp_end, esrc,
                                                                 dinv, g2b, b2, out);
}